// Round 1
// baseline (4497.546 us; speedup 1.0000x reference)
//
#include <hip/hip_runtime.h>
#include <hip/hip_bf16.h>
#include <math.h>

#define SD 32
#define NSPA 32768          // 32^3
#define NC 192
#define NB 2
#define NHD 8
#define HDIM 24

__device__ __forceinline__ float gelu_f(float x) {
    return 0.5f * x * (1.0f + erff(x * 0.70710678118654752f));
}

// ---------------------------------------------------------------------------
// Rotation matrices R[axis][h][l][3][3], mirroring the reference Rodrigues
// computation (numeric K@K) exactly.
// ---------------------------------------------------------------------------
__global__ void rot_kernel(const float* __restrict__ Ad, const float* __restrict__ Ah,
                           const float* __restrict__ Aw, float* __restrict__ R)
{
    int idx = blockIdx.x * 256 + threadIdx.x;   // 0..767
    if (idx >= 768) return;
    int l = idx & 31;
    int h = (idx >> 5) & 7;
    int axis = idx >> 8;
    const float* A = (axis == 0) ? Ad : ((axis == 1) ? Ah : Aw);
    int comp = (axis == 0) ? 2 : ((axis == 1) ? 1 : 0);
    float p = -1.0f + 2.0f * (float)l / 31.0f;
    float w0 = p * A[h * 9 + 0 * 3 + comp];
    float w1 = p * A[h * 9 + 1 * 3 + comp];
    float w2 = p * A[h * 9 + 2 * 3 + comp];
    float th = sqrtf(w0 * w0 + w1 * w1 + w2 * w2);
    th = fmaxf(th, 1e-8f);
    float ux = w0 / th, uy = w1 / th, uz = w2 / th;
    float K[3][3] = {{0.f, -uz, uy}, {uz, 0.f, -ux}, {-uy, ux, 0.f}};
    float K2[3][3];
    #pragma unroll
    for (int i = 0; i < 3; ++i)
        #pragma unroll
        for (int j = 0; j < 3; ++j) {
            float s = 0.f;
            #pragma unroll
            for (int k = 0; k < 3; ++k) s += K[i][k] * K[k][j];
            K2[i][j] = s;
        }
    float s = sinf(th), c = cosf(th);
    float* out = R + (size_t)idx * 9;
    #pragma unroll
    for (int i = 0; i < 3; ++i)
        #pragma unroll
        for (int j = 0; j < 3; ++j)
            out[i * 3 + j] = ((i == j) ? 1.0f : 0.0f) + s * K[i][j] + (1.0f - c) * K2[i][j];
}

// ---------------------------------------------------------------------------
// Circular 3x3x3 conv, fp32.  Block: 32 c_out x (4d x 4h x 32w) spatial tile.
// Thread: 4 c_out x (2 dh-combos x 8 w) = 64 accumulators.
// ---------------------------------------------------------------------------
#define CO_T 32
#define CI_T 8

__global__ __launch_bounds__(256) void conv3_kernel(const float* __restrict__ in,
        const float* __restrict__ wgt, const float* __restrict__ bias,
        float* __restrict__ out)
{
    __shared__ __align__(16) float lin[CI_T][6][6][33];
    __shared__ __align__(16) float lw[CI_T][27][36];
    int co0 = blockIdx.x * CO_T;
    int bsp = blockIdx.y;                       // 0..63
    int b   = blockIdx.z;
    int sd0 = (bsp >> 3) << 2;
    int sh0 = (bsp & 7) << 2;
    int tid = threadIdx.x;
    int wg  = tid & 3;          // w0 = wg*8
    int dhg = (tid >> 2) & 7;   // dh combos dhg, dhg+8
    int cog = tid >> 5;         // co = co0 + cog*4
    int w0  = wg << 3;

    float acc[2][8][4];
    #pragma unroll
    for (int t = 0; t < 2; ++t)
        #pragma unroll
        for (int j = 0; j < 8; ++j)
            #pragma unroll
            for (int q = 0; q < 4; ++q) acc[t][j][q] = 0.f;

    for (int cc = 0; cc < NC; cc += CI_T) {
        // input tile: 8ci x 6 x 6 x 32 = 9216 elems
        #pragma unroll
        for (int i = 0; i < 36; ++i) {
            int e = tid + 256 * i;
            int ww = e & 31;
            int r = e >> 5;
            int hh = r % 6; r /= 6;
            int dd = r % 6;
            int ci = r / 6;
            int zd = (sd0 + dd + 31) & 31;
            int zh = (sh0 + hh + 31) & 31;
            lin[ci][dd][hh][ww] =
                in[(((size_t)(b * NC + cc + ci)) << 15) + (zd << 10) + (zh << 5) + ww];
        }
        // weights: 8ci x 27tap x 32co
        #pragma unroll
        for (int i = 0; i < 27; ++i) {
            int e = tid + 256 * i;     // 0..6911
            int tap = e % 27;
            int q = e / 27;            // 0..255
            int ci = q & 7;
            int co = q >> 3;           // 0..31
            lw[ci][tap][co] = wgt[((size_t)(co0 + co) * NC + cc + ci) * 27 + tap];
        }
        __syncthreads();

        #pragma unroll 1
        for (int ci = 0; ci < CI_T; ++ci) {
            #pragma unroll
            for (int dz = 0; dz < 3; ++dz) {
                #pragma unroll
                for (int dy = 0; dy < 3; ++dy) {
                    float xv[2][10];
                    #pragma unroll
                    for (int t = 0; t < 2; ++t) {
                        int dh = dhg + t * 8;
                        int dloc = dh >> 2, hloc = dh & 3;
                        const float* rowp = &lin[ci][dloc + dz][hloc + dy][0];
                        #pragma unroll
                        for (int j = 0; j < 10; ++j)
                            xv[t][j] = rowp[(w0 + j + 31) & 31];
                    }
                    #pragma unroll
                    for (int dx = 0; dx < 3; ++dx) {
                        float4 wv = *(const float4*)&lw[ci][(dz * 3 + dy) * 3 + dx][cog << 2];
                        #pragma unroll
                        for (int t = 0; t < 2; ++t)
                            #pragma unroll
                            for (int j = 0; j < 8; ++j) {
                                float x = xv[t][j + dx];
                                acc[t][j][0] += x * wv.x;
                                acc[t][j][1] += x * wv.y;
                                acc[t][j][2] += x * wv.z;
                                acc[t][j][3] += x * wv.w;
                            }
                    }
                }
            }
        }
        __syncthreads();
    }

    #pragma unroll
    for (int t = 0; t < 2; ++t) {
        int dh = dhg + t * 8;
        int dloc = dh >> 2, hloc = dh & 3;
        size_t sp = ((size_t)(sd0 + dloc) << 10) + ((size_t)(sh0 + hloc) << 5) + w0;
        #pragma unroll
        for (int cq = 0; cq < 4; ++cq) {
            int co = co0 + (cog << 2) + cq;
            float bv = bias[co];
            size_t base = (((size_t)(b * NC + co)) << 15) + sp;
            float4 r0 = make_float4(acc[t][0][cq] + bv, acc[t][1][cq] + bv,
                                    acc[t][2][cq] + bv, acc[t][3][cq] + bv);
            float4 r1 = make_float4(acc[t][4][cq] + bv, acc[t][5][cq] + bv,
                                    acc[t][6][cq] + bv, acc[t][7][cq] + bv);
            *(float4*)&out[base]     = r0;
            *(float4*)&out[base + 4] = r1;
        }
    }
}

// ---------------------------------------------------------------------------
// Fused InstanceNorm (over spatial, per (b,c)) + exact GELU, in place.
// One block per (b,c): pass 1 reduce, pass 2 apply (data stays L2-hot).
// ---------------------------------------------------------------------------
__global__ __launch_bounds__(256) void inorm_gelu_kernel(float* __restrict__ buf)
{
    int c = blockIdx.x, b = blockIdx.y;
    size_t base = ((size_t)(b * NC + c)) << 15;
    int tid = threadIdx.x;
    const float4* p4 = (const float4*)(buf + base);
    float s = 0.f, q = 0.f;
    for (int i = tid; i < 8192; i += 256) {
        float4 v = p4[i];
        s += v.x + v.y + v.z + v.w;
        q += v.x * v.x + v.y * v.y + v.z * v.z + v.w * v.w;
    }
    #pragma unroll
    for (int off = 32; off > 0; off >>= 1) {
        s += __shfl_down(s, off);
        q += __shfl_down(q, off);
    }
    __shared__ float ls[4], lq[4];
    __shared__ float mv[2];
    if ((tid & 63) == 0) { ls[tid >> 6] = s; lq[tid >> 6] = q; }
    __syncthreads();
    if (tid == 0) {
        float S = ls[0] + ls[1] + ls[2] + ls[3];
        float Q = lq[0] + lq[1] + lq[2] + lq[3];
        float m = S / 32768.0f;
        float var = Q / 32768.0f - m * m;
        mv[0] = m;
        mv[1] = rsqrtf(var + 1e-5f);
    }
    __syncthreads();
    float m = mv[0], r = mv[1];
    float4* o4 = (float4*)(buf + base);
    for (int i = tid; i < 8192; i += 256) {
        float4 v = o4[i];
        v.x = gelu_f((v.x - m) * r);
        v.y = gelu_f((v.y - m) * r);
        v.z = gelu_f((v.z - m) * r);
        v.w = gelu_f((v.w - m) * r);
        o4[i] = v;
    }
}

// ---------------------------------------------------------------------------
// 1x1 conv as GEMM: out[b,co,p] = sum_k W[co,k] * in[b,k,p] + bias[co]
// Tile: 64co x 128pos, threads 256 (thread tile 8co x 4pos), BK=16.
// EPI 0: plain.  EPI 1: out = x * sigmoid(acc+bias)  (x at same index, M==NC)
// ---------------------------------------------------------------------------
template<int EPI>
__global__ __launch_bounds__(256) void gemm_kernel(const float* __restrict__ in,
        const float* __restrict__ wmat, const float* __restrict__ bias,
        float* __restrict__ out, const float* __restrict__ xin, int M)
{
    __shared__ __align__(16) float At[16][68];
    __shared__ __align__(16) float Bt[16][128];
    int co0 = blockIdx.x * 64;
    int p0  = blockIdx.y * 128;
    int b   = blockIdx.z;
    int tid = threadIdx.x;
    int pg  = tid & 31;     // pos = p0 + pg*4
    int cg  = tid >> 5;     // co  = co0 + cg*8
    float acc[8][4];
    #pragma unroll
    for (int i = 0; i < 8; ++i)
        #pragma unroll
        for (int j = 0; j < 4; ++j) acc[i][j] = 0.f;

    const float* inb = in + (((size_t)b * NC) << 15);
    for (int k0 = 0; k0 < NC; k0 += 16) {
        #pragma unroll
        for (int i = 0; i < 4; ++i) {
            int e = tid + 256 * i;
            int kl = e & 15, cl = e >> 4;
            At[kl][cl] = wmat[(size_t)(co0 + cl) * NC + k0 + kl];
        }
        #pragma unroll
        for (int i = 0; i < 2; ++i) {
            int e = tid + 256 * i;
            int plc = (e & 31) << 2;
            int kl = e >> 5;
            *(float4*)&Bt[kl][plc] =
                *(const float4*)&inb[((size_t)(k0 + kl) << 15) + p0 + plc];
        }
        __syncthreads();
        #pragma unroll
        for (int k = 0; k < 16; ++k) {
            float a[8], bb[4];
            *(float4*)&a[0] = *(float4*)&At[k][cg * 8];
            *(float4*)&a[4] = *(float4*)&At[k][cg * 8 + 4];
            *(float4*)&bb[0] = *(float4*)&Bt[k][pg * 4];
            #pragma unroll
            for (int i = 0; i < 8; ++i)
                #pragma unroll
                for (int j = 0; j < 4; ++j)
                    acc[i][j] += a[i] * bb[j];
        }
        __syncthreads();
    }

    #pragma unroll
    for (int i = 0; i < 8; ++i) {
        int co = co0 + cg * 8 + i;
        float bv = bias[co];
        size_t obase = (((size_t)(b * M + co)) << 15) + p0 + pg * 4;
        float4 r;
        r.x = acc[i][0] + bv; r.y = acc[i][1] + bv;
        r.z = acc[i][2] + bv; r.w = acc[i][3] + bv;
        if (EPI == 1) {
            float4 xv = *(const float4*)&xin[obase];
            r.x = xv.x / (1.0f + expf(-r.x));
            r.y = xv.y / (1.0f + expf(-r.y));
            r.z = xv.z / (1.0f + expf(-r.z));
            r.w = xv.w / (1.0f + expf(-r.w));
        }
        *(float4*)&out[obase] = r;
    }
}

// ---------------------------------------------------------------------------
// Axial attention, one wave per (b, o1, o2, head).
// qkv layout: [b][s*192 + h*24 + d][p]  (s: 0=q,1=k,2=v)
// NOTE: the reference's pos_attn bias is constant along the softmax (key)
// axis -> cancels; omitted.
// ---------------------------------------------------------------------------
__global__ __launch_bounds__(64) void attn_kernel(const float* __restrict__ qkv,
        const float* __restrict__ Rbuf, float* __restrict__ outacc,
        int axis, int accum)
{
    __shared__ __align__(16) float rq[32][28];
    __shared__ __align__(16) float rk[32][28];
    __shared__ __align__(16) float vv[32][28];
    __shared__ __align__(16) float pl[32][36];

    int o12 = blockIdx.x;
    int h   = blockIdx.y;
    int b   = blockIdx.z;
    int o1 = o12 >> 5, o2 = o12 & 31;
    int lane = threadIdx.x;
    int m  = lane & 31;
    int df = lane >> 5;

    int pbase, pstride;
    if (axis == 0)      { pbase = (o1 << 5) + o2;        pstride = 1024; }
    else if (axis == 1) { pbase = (o1 << 10) + o2;       pstride = 32; }
    else                { pbase = (o1 << 10) + (o2 << 5); pstride = 1; }

    size_t qb = ((size_t)b * 576) << 15;
    int p_m = pbase + m * pstride;

    float Rm[9];
    {
        const float* rp = Rbuf + (((size_t)axis * 8 + h) * 32 + m) * 9;
        #pragma unroll
        for (int i = 0; i < 9; ++i) Rm[i] = rp[i];
    }
    const float scale = 0.20412414523193154f;   // 24^-0.5

    // load + rotate q,k rows; load v row (each lane: row m, dims df*12..+11)
    #pragma unroll
    for (int v = 0; v < 4; ++v) {
        int d0 = (df * 4 + v) * 3;
        size_t cq = qb + (((size_t)(h * HDIM + d0)) << 15) + p_m;
        float q0 = qkv[cq];
        float q1 = qkv[cq + (1u << 15)];
        float q2 = qkv[cq + (2u << 15)];
        rq[m][d0 + 0] = (Rm[0] * q0 + Rm[1] * q1 + Rm[2] * q2) * scale;
        rq[m][d0 + 1] = (Rm[3] * q0 + Rm[4] * q1 + Rm[5] * q2) * scale;
        rq[m][d0 + 2] = (Rm[6] * q0 + Rm[7] * q1 + Rm[8] * q2) * scale;
        size_t ck = qb + (((size_t)(NC + h * HDIM + d0)) << 15) + p_m;
        float k0 = qkv[ck];
        float k1 = qkv[ck + (1u << 15)];
        float k2 = qkv[ck + (2u << 15)];
        rk[m][d0 + 0] = Rm[0] * k0 + Rm[1] * k1 + Rm[2] * k2;
        rk[m][d0 + 1] = Rm[3] * k0 + Rm[4] * k1 + Rm[5] * k2;
        rk[m][d0 + 2] = Rm[6] * k0 + Rm[7] * k1 + Rm[8] * k2;
    }
    #pragma unroll
    for (int i = 0; i < 12; ++i) {
        int d = df * 12 + i;
        vv[m][d] = qkv[qb + (((size_t)(2 * NC + h * HDIM + d)) << 15) + p_m];
    }
    __syncthreads();

    // logits: lane (l=m, half df) computes 16 keys
    float qrow[24];
    #pragma unroll
    for (int i = 0; i < 6; ++i)
        *(float4*)&qrow[i * 4] = *(float4*)&rq[m][i * 4];
    float pv[16];
    float mymax = -1e30f;
    #pragma unroll
    for (int j = 0; j < 16; ++j) {
        int mm = df * 16 + j;
        float s = 0.f;
        #pragma unroll
        for (int d = 0; d < 24; d += 4) {
            float4 kk = *(float4*)&rk[mm][d];
            s += qrow[d] * kk.x + qrow[d + 1] * kk.y + qrow[d + 2] * kk.z + qrow[d + 3] * kk.w;
        }
        pv[j] = s;
        mymax = fmaxf(mymax, s);
    }
    float rmax = fmaxf(mymax, __shfl_xor(mymax, 32));
    float mysum = 0.f;
    #pragma unroll
    for (int j = 0; j < 16; ++j) {
        pv[j] = expf(pv[j] - rmax);
        mysum += pv[j];
    }
    float rsum = mysum + __shfl_xor(mysum, 32);
    float inv = 1.0f / rsum;
    #pragma unroll
    for (int j = 0; j < 16; ++j) pl[m][df * 16 + j] = pv[j] * inv;
    __syncthreads();

    // PV: lane (l=m, df) computes out dims df*12..+11
    float prow[32];
    #pragma unroll
    for (int i = 0; i < 8; ++i)
        *(float4*)&prow[i * 4] = *(float4*)&pl[m][i * 4];
    float o[12];
    #pragma unroll
    for (int i = 0; i < 12; ++i) o[i] = 0.f;
    #pragma unroll
    for (int mm = 0; mm < 32; ++mm) {
        float p = prow[mm];
        float4 v0 = *(float4*)&vv[mm][df * 12];
        float4 v1 = *(float4*)&vv[mm][df * 12 + 4];
        float4 v2 = *(float4*)&vv[mm][df * 12 + 8];
        o[0] += p * v0.x; o[1]  += p * v0.y; o[2]  += p * v0.z; o[3]  += p * v0.w;
        o[4] += p * v1.x; o[5]  += p * v1.y; o[6]  += p * v1.z; o[7]  += p * v1.w;
        o[8] += p * v2.x; o[9]  += p * v2.y; o[10] += p * v2.z; o[11] += p * v2.w;
    }
    size_t ob = ((size_t)(b * NC)) << 15;
    int p_l = pbase + m * pstride;
    #pragma unroll
    for (int i = 0; i < 12; ++i) {
        size_t a = ob + (((size_t)(h * HDIM + df * 12 + i)) << 15) + p_l;
        if (accum) outacc[a] += o[i];
        else       outacc[a] = o[i];
    }
}

// ---------------------------------------------------------------------------
extern "C" void kernel_launch(void* const* d_in, const int* in_sizes, int n_in,
                              void* d_out, int out_size, void* d_ws, size_t ws_size,
                              hipStream_t stream)
{
    (void)in_sizes; (void)n_in; (void)out_size; (void)ws_size;
    const float* x      = (const float*)d_in[0];
    const float* pos    = (const float*)d_in[1];
    const float* lp1_w  = (const float*)d_in[2];
    const float* lp1_b  = (const float*)d_in[3];
    const float* lp2_w  = (const float*)d_in[4];
    const float* lp2_b  = (const float*)d_in[5];
    const float* m1_w   = (const float*)d_in[6];
    const float* m1_b   = (const float*)d_in[7];
    const float* m2_w   = (const float*)d_in[8];
    const float* m2_b   = (const float*)d_in[9];
    // d_in[10]=pa_w, d_in[11]=pa_b: per-query softmax bias, cancels -> unused
    const float* qkv_w  = (const float*)d_in[12];
    const float* qkv_b  = (const float*)d_in[13];
    const float* A_d    = (const float*)d_in[14];
    const float* A_h    = (const float*)d_in[15];
    const float* A_w    = (const float*)d_in[16];
    const float* proj_w = (const float*)d_in[17];
    const float* proj_b = (const float*)d_in[18];

    float* ws   = (float*)d_ws;
    float* Rbuf = ws;                       // 6912 floats
    float* buf1 = ws + 8192;                // 12,582,912
    float* buf2 = buf1 + 12582912;          // 12,582,912
    float* qkvb = buf2 + 12582912;          // 37,748,736

    rot_kernel<<<dim3(3), 256, 0, stream>>>(A_d, A_h, A_w, Rbuf);

    // local path
    conv3_kernel<<<dim3(6, 64, 2), 256, 0, stream>>>(pos, lp1_w, lp1_b, buf1);
    inorm_gelu_kernel<<<dim3(192, 2), 256, 0, stream>>>(buf1);
    gemm_kernel<0><<<dim3(3, 256, 2), 256, 0, stream>>>(buf1, lp2_w, lp2_b, buf2, nullptr, 192);
    // modulation path
    gemm_kernel<0><<<dim3(3, 256, 2), 256, 0, stream>>>(buf2, m1_w, m1_b, buf1, nullptr, 192);
    inorm_gelu_kernel<<<dim3(192, 2), 256, 0, stream>>>(buf1);
    gemm_kernel<1><<<dim3(3, 256, 2), 256, 0, stream>>>(buf1, m2_w, m2_b, buf2, x, 192);
    // qkv once (identical for all three axes)
    gemm_kernel<0><<<dim3(9, 256, 2), 256, 0, stream>>>(buf2, qkv_w, qkv_b, qkvb, nullptr, 576);
    // three axial attentions accumulated into buf1
    attn_kernel<<<dim3(1024, 8, 2), 64, 0, stream>>>(qkvb, Rbuf, buf1, 0, 0);
    attn_kernel<<<dim3(1024, 8, 2), 64, 0, stream>>>(qkvb, Rbuf, buf1, 1, 1);
    attn_kernel<<<dim3(1024, 8, 2), 64, 0, stream>>>(qkvb, Rbuf, buf1, 2, 1);
    // final projection
    gemm_kernel<0><<<dim3(3, 256, 2), 256, 0, stream>>>(buf1, proj_w, proj_b, (float*)d_out, nullptr, 192);
}

// Round 2
// 1737.697 us; speedup vs baseline: 2.5882x; 2.5882x over previous
//
#include <hip/hip_runtime.h>
#include <hip/hip_bf16.h>
#include <math.h>

#define SD 32
#define NSPA 32768          // 32^3
#define NC 192
#define NB 2
#define NHD 8
#define HDIM 24

typedef __bf16 bf16x8 __attribute__((ext_vector_type(8)));
typedef float f32x4 __attribute__((ext_vector_type(4)));

__device__ __forceinline__ float gelu_f(float x) {
    return 0.5f * x * (1.0f + erff(x * 0.70710678118654752f));
}

__device__ __forceinline__ ushort bfr(float x) {   // fp32 -> bf16 bits, RNE
    unsigned u = __float_as_uint(x);
    unsigned r = (u + 0x7fffu + ((u >> 16) & 1u)) >> 16;
    return (ushort)r;
}

// ---------------------------------------------------------------------------
// Rotation matrices R[axis][h][l][3][3] (Rodrigues, numeric K@K like ref)
// ---------------------------------------------------------------------------
__global__ void rot_kernel(const float* __restrict__ Ad, const float* __restrict__ Ah,
                           const float* __restrict__ Aw, float* __restrict__ R)
{
    int idx = blockIdx.x * 256 + threadIdx.x;   // 0..767
    if (idx >= 768) return;
    int l = idx & 31;
    int h = (idx >> 5) & 7;
    int axis = idx >> 8;
    const float* A = (axis == 0) ? Ad : ((axis == 1) ? Ah : Aw);
    int comp = (axis == 0) ? 2 : ((axis == 1) ? 1 : 0);
    float p = -1.0f + 2.0f * (float)l / 31.0f;
    float w0 = p * A[h * 9 + 0 * 3 + comp];
    float w1 = p * A[h * 9 + 1 * 3 + comp];
    float w2 = p * A[h * 9 + 2 * 3 + comp];
    float th = sqrtf(w0 * w0 + w1 * w1 + w2 * w2);
    th = fmaxf(th, 1e-8f);
    float ux = w0 / th, uy = w1 / th, uz = w2 / th;
    float K[3][3] = {{0.f, -uz, uy}, {uz, 0.f, -ux}, {-uy, ux, 0.f}};
    float K2[3][3];
    #pragma unroll
    for (int i = 0; i < 3; ++i)
        #pragma unroll
        for (int j = 0; j < 3; ++j) {
            float s = 0.f;
            #pragma unroll
            for (int k = 0; k < 3; ++k) s += K[i][k] * K[k][j];
            K2[i][j] = s;
        }
    float s = sinf(th), c = cosf(th);
    float* out = R + (size_t)idx * 9;
    #pragma unroll
    for (int i = 0; i < 3; ++i)
        #pragma unroll
        for (int j = 0; j < 3; ++j)
            out[i * 3 + j] = ((i == j) ? 1.0f : 0.0f) + s * K[i][j] + (1.0f - c) * K2[i][j];
}

// ---------------------------------------------------------------------------
// Input repack: pos_emb fp32 [b][ci][32768] -> xb bf16 split-hi/lo
// layout [b][cc48][pos 32768][8]  (8 = 4 orig ci x {hi,lo})
// ---------------------------------------------------------------------------
__global__ __launch_bounds__(256) void xcvt_kernel(const float* __restrict__ in,
                                                   ushort* __restrict__ xb)
{
    __shared__ float lds[192][66];
    int t = threadIdx.x;
    int pos0 = blockIdx.x * 64;
    int b = blockIdx.y;
    #pragma unroll 4
    for (int i = 0; i < 48; ++i) {
        int idx = t + 256 * i;
        int ci = idx >> 6, col = idx & 63;
        lds[ci][col] = in[((size_t)(b * NC + ci) << 15) + pos0 + col];
    }
    __syncthreads();
    int p = t & 63;
    int ccb = t >> 6;
    #pragma unroll
    for (int i = 0; i < 12; ++i) {
        int cc = i * 4 + ccb;
        unsigned ov[4];
        #pragma unroll
        for (int k = 0; k < 4; ++k) {
            float x = lds[cc * 4 + k][p];
            ushort hi = bfr(x);
            float hif = __uint_as_float((unsigned)hi << 16);
            ushort lo = bfr(x - hif);
            ov[k] = (unsigned)hi | ((unsigned)lo << 16);
        }
        *(uint4*)(xb + ((((size_t)(b * 48 + cc)) << 15) + pos0 + p) * 8) = *(uint4*)ov;
    }
}

// ---------------------------------------------------------------------------
// Weight repack: lp1_w fp32 [co][ci][27] -> wb bf16 [cc48][tap28][co192][8]
// (tap 27 zero-padded; 8 = 4 orig ci x duplicated pair to match hi/lo)
// ---------------------------------------------------------------------------
__global__ __launch_bounds__(256) void wcvt_kernel(const float* __restrict__ wgt,
                                                   ushort* __restrict__ wb)
{
    int slot = blockIdx.x * 256 + threadIdx.x;
    if (slot >= 48 * 28 * 192) return;
    int cc = slot / (28 * 192);
    int r = slot % (28 * 192);
    int tap = r / 192, co = r % 192;
    unsigned ov[4];
    #pragma unroll
    for (int k = 0; k < 4; ++k) {
        int ci = cc * 4 + k;
        float w = (tap < 27) ? wgt[((size_t)co * NC + ci) * 27 + tap] : 0.f;
        ushort wv = bfr(w);
        ov[k] = (unsigned)wv | ((unsigned)wv << 16);
    }
    *(uint4*)(wb + (size_t)slot * 8) = *(uint4*)ov;
}

// ---------------------------------------------------------------------------
// Circular 3x3x3 conv as implicit-GEMM MFMA (bf16, hi/lo split input).
// Block: 64co x (2d x 8h x 32w) = 64 x 512. 4 waves, wave tile m4 x n8.
// K-chunk = 8 eff-ci x 28 taps = 7 MFMA K-steps; 48 chunks.
// ---------------------------------------------------------------------------
#define LIN_BYTES (4 * 10 * 32 * 16)   // 20480
#define LW_BYTES  (28 * 65 * 16)       // 29120

__global__ __launch_bounds__(256, 2) void conv3_mfma(
        const ushort* __restrict__ xb, const ushort* __restrict__ wb,
        const float* __restrict__ bias, float* __restrict__ out)
{
    __shared__ __align__(16) char smem[LIN_BYTES + LW_BYTES];
    char* lin = smem;
    char* lw  = smem + LIN_BYTES;
    int tid = threadIdx.x;
    int co0 = blockIdx.x * 64;
    int sp  = blockIdx.y;               // 0..63
    int b   = blockIdx.z;
    int d0 = (sp >> 2) * 2;
    int h0 = (sp & 3) * 8;
    int lane = tid & 63, wv = tid >> 6;
    int g = lane >> 4, c = lane & 15;

    // per-lane fragment address precompute
    int aoff[7], brow[7], bdx[7];
    #pragma unroll
    for (int s = 0; s < 7; ++s) {
        int tap = 4 * s + g;
        aoff[s] = (tap * 65 + c) * 16;
        int tc = tap > 26 ? 26 : tap;   // clamp for B (A weight is zero there)
        int dz = tc / 9, r = tc % 9, dy = r / 3, dx = r % 3;
        brow[s] = (dz * 10 + dy) * 512;
        bdx[s] = dx - 1;
    }
    int nb[8], wn[8];
    #pragma unroll
    for (int n = 0; n < 8; ++n) {
        int posl = wv * 128 + n * 16 + c;
        int dof = posl >> 8, rem = posl & 255;
        nb[n] = dof * 5120 + (rem >> 5) * 512;
        wn[n] = rem & 31;
    }

    // staging offsets (chunk-invariant)
    int xoff[5];          // element offsets into xb (per chunk: + base)
    #pragma unroll
    for (int k = 0; k < 5; ++k) {
        int i = tid + 256 * k;           // 0..1279
        int dz = i / 320, r2 = i % 320, hh = r2 >> 5, ww = r2 & 31;
        int dd = (d0 + dz + 31) & 31, hg = (h0 + hh + 31) & 31;
        xoff[k] = (dd << 10) + (hg << 5) + ww;
    }
    int wtap = 0, wco = 0;
    {
        // weight slots: i = tid + 256k -> tap = i>>6, co = i&63 (co = lane)
        wco = tid & 63;
        wtap = tid >> 6;                  // base tap for k=0; +4 per k
    }

    f32x4 acc[4][8];
    #pragma unroll
    for (int m = 0; m < 4; ++m)
        #pragma unroll
        for (int n = 0; n < 8; ++n)
            acc[m][n] = (f32x4){0.f, 0.f, 0.f, 0.f};

    const size_t xbb = ((size_t)b * 48) << 15;

    for (int cc = 0; cc < 48; ++cc) {
        // ---- stage input (1280 x 16B) ----
        const ushort* xsrc = xb + ((xbb + ((size_t)cc << 15)) << 3);
        uint4 xi[5];
        #pragma unroll
        for (int k = 0; k < 5; ++k)
            xi[k] = *(const uint4*)(xsrc + ((size_t)xoff[k] << 3));
        // ---- stage weights (1792 x 16B) ----
        const ushort* wsrc = wb + (((size_t)cc * 28 * 192) << 3);
        uint4 wi[7];
        #pragma unroll
        for (int k = 0; k < 7; ++k) {
            int tap = wtap + 4 * k;
            wi[k] = *(const uint4*)(wsrc + (((size_t)tap * 192 + co0 + wco) << 3));
        }
        #pragma unroll
        for (int k = 0; k < 5; ++k)
            *(uint4*)(lin + (tid + 256 * k) * 16) = xi[k];
        #pragma unroll
        for (int k = 0; k < 7; ++k)
            *(uint4*)(lw + ((wtap + 4 * k) * 65 + wco) * 16) = wi[k];
        __syncthreads();

        // ---- compute: 7 K-steps of 32 (4 taps x 8 eff-ci) ----
        #pragma unroll
        for (int s = 0; s < 7; ++s) {
            bf16x8 a[4];
            #pragma unroll
            for (int m = 0; m < 4; ++m)
                a[m] = *(const bf16x8*)(lw + aoff[s] + m * 256);
            #pragma unroll
            for (int n = 0; n < 8; ++n) {
                bf16x8 bv = *(const bf16x8*)(lin + nb[n] + brow[s] +
                                             (((wn[n] + bdx[s]) & 31) << 4));
                #pragma unroll
                for (int m = 0; m < 4; ++m)
                    acc[m][n] = __builtin_amdgcn_mfma_f32_16x16x32_bf16(a[m], bv, acc[m][n], 0, 0, 0);
            }
        }
        __syncthreads();
    }

    // ---- epilogue: bias + store fp32 NCDHW ----
    float bv[4][4];
    #pragma unroll
    for (int m = 0; m < 4; ++m)
        #pragma unroll
        for (int r = 0; r < 4; ++r)
            bv[m][r] = bias[co0 + m * 16 + g * 4 + r];
    #pragma unroll
    for (int n = 0; n < 8; ++n) {
        int posl = wv * 128 + n * 16 + c;
        int dof = posl >> 8, rem = posl & 255;
        size_t spo = (size_t)(d0 + dof) * 1024 + (size_t)(h0 + (rem >> 5)) * 32 + (rem & 31);
        #pragma unroll
        for (int m = 0; m < 4; ++m) {
            int co = co0 + m * 16 + g * 4;
            #pragma unroll
            for (int r = 0; r < 4; ++r)
                out[((size_t)(b * NC + co + r) << 15) + spo] = acc[m][n][r] + bv[m][r];
        }
    }
}

// ---------------------------------------------------------------------------
// Fused InstanceNorm + exact GELU, in place. One block per (b,c).
// ---------------------------------------------------------------------------
__global__ __launch_bounds__(256) void inorm_gelu_kernel(float* __restrict__ buf)
{
    int c = blockIdx.x, b = blockIdx.y;
    size_t base = ((size_t)(b * NC + c)) << 15;
    int tid = threadIdx.x;
    const float4* p4 = (const float4*)(buf + base);
    float s = 0.f, q = 0.f;
    for (int i = tid; i < 8192; i += 256) {
        float4 v = p4[i];
        s += v.x + v.y + v.z + v.w;
        q += v.x * v.x + v.y * v.y + v.z * v.z + v.w * v.w;
    }
    #pragma unroll
    for (int off = 32; off > 0; off >>= 1) {
        s += __shfl_down(s, off);
        q += __shfl_down(q, off);
    }
    __shared__ float ls[4], lq[4];
    __shared__ float mv[2];
    if ((tid & 63) == 0) { ls[tid >> 6] = s; lq[tid >> 6] = q; }
    __syncthreads();
    if (tid == 0) {
        float S = ls[0] + ls[1] + ls[2] + ls[3];
        float Q = lq[0] + lq[1] + lq[2] + lq[3];
        float m = S / 32768.0f;
        float var = Q / 32768.0f - m * m;
        mv[0] = m;
        mv[1] = rsqrtf(var + 1e-5f);
    }
    __syncthreads();
    float m = mv[0], r = mv[1];
    float4* o4 = (float4*)(buf + base);
    for (int i = tid; i < 8192; i += 256) {
        float4 v = o4[i];
        v.x = gelu_f((v.x - m) * r);
        v.y = gelu_f((v.y - m) * r);
        v.z = gelu_f((v.z - m) * r);
        v.w = gelu_f((v.w - m) * r);
        o4[i] = v;
    }
}

// ---------------------------------------------------------------------------
// 1x1 conv as fp32 GEMM. Tile 64co x 128pos, 256 thr (8co x 4pos each), BK=16.
// EPI 0: plain.  EPI 1: out = x * sigmoid(acc+bias)
// ---------------------------------------------------------------------------
template<int EPI>
__global__ __launch_bounds__(256) void gemm_kernel(const float* __restrict__ in,
        const float* __restrict__ wmat, const float* __restrict__ bias,
        float* __restrict__ out, const float* __restrict__ xin, int M)
{
    __shared__ __align__(16) float At[16][68];
    __shared__ __align__(16) float Bt[16][128];
    int co0 = blockIdx.x * 64;
    int p0  = blockIdx.y * 128;
    int b   = blockIdx.z;
    int tid = threadIdx.x;
    int pg  = tid & 31;
    int cg  = tid >> 5;
    float acc[8][4];
    #pragma unroll
    for (int i = 0; i < 8; ++i)
        #pragma unroll
        for (int j = 0; j < 4; ++j) acc[i][j] = 0.f;

    const float* inb = in + (((size_t)b * NC) << 15);
    for (int k0 = 0; k0 < NC; k0 += 16) {
        #pragma unroll
        for (int i = 0; i < 4; ++i) {
            int e = tid + 256 * i;
            int kl = e & 15, cl = e >> 4;
            At[kl][cl] = wmat[(size_t)(co0 + cl) * NC + k0 + kl];
        }
        #pragma unroll
        for (int i = 0; i < 2; ++i) {
            int e = tid + 256 * i;
            int plc = (e & 31) << 2;
            int kl = e >> 5;
            *(float4*)&Bt[kl][plc] =
                *(const float4*)&inb[((size_t)(k0 + kl) << 15) + p0 + plc];
        }
        __syncthreads();
        #pragma unroll
        for (int k = 0; k < 16; ++k) {
            float a[8], bb[4];
            *(float4*)&a[0] = *(float4*)&At[k][cg * 8];
            *(float4*)&a[4] = *(float4*)&At[k][cg * 8 + 4];
            *(float4*)&bb[0] = *(float4*)&Bt[k][pg * 4];
            #pragma unroll
            for (int i = 0; i < 8; ++i)
                #pragma unroll
                for (int j = 0; j < 4; ++j)
                    acc[i][j] += a[i] * bb[j];
        }
        __syncthreads();
    }

    #pragma unroll
    for (int i = 0; i < 8; ++i) {
        int co = co0 + cg * 8 + i;
        float bvv = bias[co];
        size_t obase = (((size_t)(b * M + co)) << 15) + p0 + pg * 4;
        float4 r;
        r.x = acc[i][0] + bvv; r.y = acc[i][1] + bvv;
        r.z = acc[i][2] + bvv; r.w = acc[i][3] + bvv;
        if (EPI == 1) {
            float4 xv = *(const float4*)&xin[obase];
            r.x = xv.x / (1.0f + expf(-r.x));
            r.y = xv.y / (1.0f + expf(-r.y));
            r.z = xv.z / (1.0f + expf(-r.z));
            r.w = xv.w / (1.0f + expf(-r.w));
        }
        *(float4*)&out[obase] = r;
    }
}

// ---------------------------------------------------------------------------
// Axial attention, one wave per (b, o1, o2, head). pos_attn bias cancels.
// ---------------------------------------------------------------------------
__global__ __launch_bounds__(64) void attn_kernel(const float* __restrict__ qkv,
        const float* __restrict__ Rbuf, float* __restrict__ outacc,
        int axis, int accum)
{
    __shared__ __align__(16) float rq[32][28];
    __shared__ __align__(16) float rk[32][28];
    __shared__ __align__(16) float vv[32][28];
    __shared__ __align__(16) float pl[32][36];

    int o12 = blockIdx.x;
    int h   = blockIdx.y;
    int b   = blockIdx.z;
    int o1 = o12 >> 5, o2 = o12 & 31;
    int lane = threadIdx.x;
    int m  = lane & 31;
    int df = lane >> 5;

    int pbase, pstride;
    if (axis == 0)      { pbase = (o1 << 5) + o2;        pstride = 1024; }
    else if (axis == 1) { pbase = (o1 << 10) + o2;       pstride = 32; }
    else                { pbase = (o1 << 10) + (o2 << 5); pstride = 1; }

    size_t qb = ((size_t)b * 576) << 15;
    int p_m = pbase + m * pstride;

    float Rm[9];
    {
        const float* rp = Rbuf + (((size_t)axis * 8 + h) * 32 + m) * 9;
        #pragma unroll
        for (int i = 0; i < 9; ++i) Rm[i] = rp[i];
    }
    const float scale = 0.20412414523193154f;

    #pragma unroll
    for (int v = 0; v < 4; ++v) {
        int d0 = (df * 4 + v) * 3;
        size_t cq = qb + (((size_t)(h * HDIM + d0)) << 15) + p_m;
        float q0 = qkv[cq];
        float q1 = qkv[cq + (1u << 15)];
        float q2 = qkv[cq + (2u << 15)];
        rq[m][d0 + 0] = (Rm[0] * q0 + Rm[1] * q1 + Rm[2] * q2) * scale;
        rq[m][d0 + 1] = (Rm[3] * q0 + Rm[4] * q1 + Rm[5] * q2) * scale;
        rq[m][d0 + 2] = (Rm[6] * q0 + Rm[7] * q1 + Rm[8] * q2) * scale;
        size_t ck = qb + (((size_t)(NC + h * HDIM + d0)) << 15) + p_m;
        float k0 = qkv[ck];
        float k1 = qkv[ck + (1u << 15)];
        float k2 = qkv[ck + (2u << 15)];
        rk[m][d0 + 0] = Rm[0] * k0 + Rm[1] * k1 + Rm[2] * k2;
        rk[m][d0 + 1] = Rm[3] * k0 + Rm[4] * k1 + Rm[5] * k2;
        rk[m][d0 + 2] = Rm[6] * k0 + Rm[7] * k1 + Rm[8] * k2;
    }
    #pragma unroll
    for (int i = 0; i < 12; ++i) {
        int d = df * 12 + i;
        vv[m][d] = qkv[qb + (((size_t)(2 * NC + h * HDIM + d)) << 15) + p_m];
    }
    __syncthreads();

    float qrow[24];
    #pragma unroll
    for (int i = 0; i < 6; ++i)
        *(float4*)&qrow[i * 4] = *(float4*)&rq[m][i * 4];
    float pv[16];
    float mymax = -1e30f;
    #pragma unroll
    for (int j = 0; j < 16; ++j) {
        int mm = df * 16 + j;
        float s = 0.f;
        #pragma unroll
        for (int d = 0; d < 24; d += 4) {
            float4 kk = *(float4*)&rk[mm][d];
            s += qrow[d] * kk.x + qrow[d + 1] * kk.y + qrow[d + 2] * kk.z + qrow[d + 3] * kk.w;
        }
        pv[j] = s;
        mymax = fmaxf(mymax, s);
    }
    float rmax = fmaxf(mymax, __shfl_xor(mymax, 32));
    float mysum = 0.f;
    #pragma unroll
    for (int j = 0; j < 16; ++j) {
        pv[j] = expf(pv[j] - rmax);
        mysum += pv[j];
    }
    float rsum = mysum + __shfl_xor(mysum, 32);
    float inv = 1.0f / rsum;
    #pragma unroll
    for (int j = 0; j < 16; ++j) pl[m][df * 16 + j] = pv[j] * inv;
    __syncthreads();

    float prow[32];
    #pragma unroll
    for (int i = 0; i < 8; ++i)
        *(float4*)&prow[i * 4] = *(float4*)&pl[m][i * 4];
    float o[12];
    #pragma unroll
    for (int i = 0; i < 12; ++i) o[i] = 0.f;
    #pragma unroll
    for (int mm = 0; mm < 32; ++mm) {
        float p = prow[mm];
        float4 v0 = *(float4*)&vv[mm][df * 12];
        float4 v1 = *(float4*)&vv[mm][df * 12 + 4];
        float4 v2 = *(float4*)&vv[mm][df * 12 + 8];
        o[0] += p * v0.x; o[1]  += p * v0.y; o[2]  += p * v0.z; o[3]  += p * v0.w;
        o[4] += p * v1.x; o[5]  += p * v1.y; o[6]  += p * v1.z; o[7]  += p * v1.w;
        o[8] += p * v2.x; o[9]  += p * v2.y; o[10] += p * v2.z; o[11] += p * v2.w;
    }
    size_t ob = ((size_t)(b * NC)) << 15;
    int p_l = pbase + m * pstride;
    #pragma unroll
    for (int i = 0; i < 12; ++i) {
        size_t a = ob + (((size_t)(h * HDIM + df * 12 + i)) << 15) + p_l;
        if (accum) outacc[a] += o[i];
        else       outacc[a] = o[i];
    }
}

// ---------------------------------------------------------------------------
extern "C" void kernel_launch(void* const* d_in, const int* in_sizes, int n_in,
                              void* d_out, int out_size, void* d_ws, size_t ws_size,
                              hipStream_t stream)
{
    (void)in_sizes; (void)n_in; (void)out_size; (void)ws_size;
    const float* x      = (const float*)d_in[0];
    const float* pos    = (const float*)d_in[1];
    const float* lp1_w  = (const float*)d_in[2];
    const float* lp1_b  = (const float*)d_in[3];
    const float* lp2_w  = (const float*)d_in[4];
    const float* lp2_b  = (const float*)d_in[5];
    const float* m1_w   = (const float*)d_in[6];
    const float* m1_b   = (const float*)d_in[7];
    const float* m2_w   = (const float*)d_in[8];
    const float* m2_b   = (const float*)d_in[9];
    // d_in[10]=pa_w, d_in[11]=pa_b: per-query softmax bias, cancels -> unused
    const float* qkv_w  = (const float*)d_in[12];
    const float* qkv_b  = (const float*)d_in[13];
    const float* A_d    = (const float*)d_in[14];
    const float* A_h    = (const float*)d_in[15];
    const float* A_w    = (const float*)d_in[16];
    const float* proj_w = (const float*)d_in[17];
    const float* proj_b = (const float*)d_in[18];

    float* ws   = (float*)d_ws;
    float* Rbuf = ws;                       // 8192 floats
    float* buf1 = ws + 8192;                // 12,582,912 floats
    float* X    = buf1 + 12582912;          // region: 50,331,648 floats
    // conv phase aliases:
    ushort* xb2 = (ushort*)X;               // 25,165,824 ushorts (50.3 MB)
    ushort* wb2 = xb2 + 25165824;           //  2,064,384 ushorts ( 4.1 MB)
    // post-conv aliases:
    float* buf2 = X;                        // 12,582,912 floats
    float* qkvb = X + 12582912;             // 37,748,736 floats

    rot_kernel<<<dim3(3), 256, 0, stream>>>(A_d, A_h, A_w, Rbuf);
    xcvt_kernel<<<dim3(512, 2), 256, 0, stream>>>(pos, xb2);
    wcvt_kernel<<<dim3(1008), 256, 0, stream>>>(lp1_w, wb2);
    conv3_mfma<<<dim3(3, 64, 2), 256, 0, stream>>>(xb2, wb2, lp1_b, buf1);

    inorm_gelu_kernel<<<dim3(192, 2), 256, 0, stream>>>(buf1);
    gemm_kernel<0><<<dim3(3, 256, 2), 256, 0, stream>>>(buf1, lp2_w, lp2_b, buf2, nullptr, 192);
    gemm_kernel<0><<<dim3(3, 256, 2), 256, 0, stream>>>(buf2, m1_w, m1_b, buf1, nullptr, 192);
    inorm_gelu_kernel<<<dim3(192, 2), 256, 0, stream>>>(buf1);
    gemm_kernel<1><<<dim3(3, 256, 2), 256, 0, stream>>>(buf1, m2_w, m2_b, buf2, x, 192);
    gemm_kernel<0><<<dim3(9, 256, 2), 256, 0, stream>>>(buf2, qkv_w, qkv_b, qkvb, nullptr, 576);
    attn_kernel<<<dim3(1024, 8, 2), 64, 0, stream>>>(qkvb, Rbuf, buf1, 0, 0);
    attn_kernel<<<dim3(1024, 8, 2), 64, 0, stream>>>(qkvb, Rbuf, buf1, 1, 1);
    attn_kernel<<<dim3(1024, 8, 2), 64, 0, stream>>>(qkvb, Rbuf, buf1, 2, 1);
    gemm_kernel<0><<<dim3(3, 256, 2), 256, 0, stream>>>(buf1, proj_w, proj_b, (float*)d_out, nullptr, 192);
}